// Round 8
// baseline (609.001 us; speedup 1.0000x reference)
//
#include <hip/hip_runtime.h>

#define NFFT 16384
#define LSIG 8192
#define NH   1024
#define NTH  1024    // main kernels
#define FTH  512     // fallback kernel
#define LDSN (NFFT + (NFFT >> 5))   // pad every 32 floats

__device__ __forceinline__ int PADI(int i) { return i + (i >> 5); }

struct cplx { float x, y; };
__device__ __forceinline__ cplx cadd(cplx a, cplx b){ return {a.x+b.x, a.y+b.y}; }
__device__ __forceinline__ cplx csub(cplx a, cplx b){ return {a.x-b.x, a.y-b.y}; }
__device__ __forceinline__ cplx cmul(cplx a, cplx b){ return {a.x*b.x - a.y*b.y, a.x*b.y + a.y*b.x}; }

constexpr float W32C[16] = {
  1.0f, 0.9807852804f, 0.9238795325f, 0.8314696123f,
  0.7071067812f, 0.5555702330f, 0.3826834324f, 0.1950903220f,
  0.0f, -0.1950903220f, -0.3826834324f, -0.5555702330f,
  -0.7071067812f, -0.8314696123f, -0.9238795325f, -0.9807852804f };
constexpr float W32S[16] = {
  0.0f, 0.1950903220f, 0.3826834324f, 0.5555702330f,
  0.7071067812f, 0.8314696123f, 0.9238795325f, 0.9807852804f,
  1.0f, 0.9807852804f, 0.9238795325f, 0.8314696123f,
  0.7071067812f, 0.5555702330f, 0.3826834324f, 0.1950903220f };
constexpr int BR3[8] = {0,4,2,6,1,5,3,7};

// Radix-2 pass, compile-time span SP -> constant indices -> registers.
template<int N, int SP, bool INV>
__device__ __forceinline__ void fft_pass(cplx* z) {
  #pragma unroll
  for (int b = 0; b < N; b += 2*SP) {
    #pragma unroll
    for (int r = 0; r < SP; ++r) {
      const int kk = r * (16 / SP);
      if (!INV) {
        cplx u = z[b+r], v = z[b+r+SP];
        z[b+r] = cadd(u, v);
        cplx d = csub(u, v);
        z[b+r+SP] = cmul(d, cplx{W32C[kk], -W32S[kk]});
      } else {
        cplx t0 = z[b+r], t1 = z[b+r+SP];
        cplx w = cmul(t1, cplx{W32C[kk], W32S[kk]});
        z[b+r]    = cadd(t0, w);
        z[b+r+SP] = csub(t0, w);
      }
    }
  }
}

template<int N, bool INV>
__device__ __forceinline__ void fft_regs(cplx* z) {
  if constexpr (!INV) {
    if constexpr (N >= 32) fft_pass<N,16,false>(z);
    if constexpr (N >= 16) fft_pass<N, 8,false>(z);
    if constexpr (N >=  8) fft_pass<N, 4,false>(z);
    if constexpr (N >=  4) fft_pass<N, 2,false>(z);
    fft_pass<N,1,false>(z);
  } else {
    fft_pass<N,1,true>(z);
    if constexpr (N >=  4) fft_pass<N, 2,true>(z);
    if constexpr (N >=  8) fft_pass<N, 4,true>(z);
    if constexpr (N >= 16) fft_pass<N, 8,true>(z);
    if constexpr (N >= 32) fft_pass<N,16,true>(z);
  }
}

// LDS radix-8 stage for S >= 32, templated on thread count NT.
template<int NT, int S, bool INV>
__device__ __forceinline__ void stage8(float* sre, float* sim, int tid) {
  const float ang1 = (INV ? 2.0f : -2.0f) * 3.14159265358979f / (float)(8 * S);
  #pragma unroll
  for (int it = 0; it < (NFFT/8)/NT; ++it) {
    int bf = tid + it * NT;
    int q = bf / S;
    int r = bf - q * S;
    int base = q * (8 * S) + r;
    float t = ang1 * (float)r;
    cplx w1 = {__cosf(t), __sinf(t)};
    cplx wp[8];
    wp[0] = {1.0f, 0.0f};
    #pragma unroll
    for (int m = 1; m < 8; ++m) wp[m] = cmul(wp[m-1], w1);

    cplx a[8];
    if (!INV) {
      #pragma unroll
      for (int j = 0; j < 8; ++j) { int idx = PADI(base + j*S); a[j] = {sre[idx], sim[idx]}; }
      fft_regs<8,false>(a);
      #pragma unroll
      for (int p = 0; p < 8; ++p) {
        const int m = BR3[p];
        cplx o = cmul(a[p], wp[m]);
        int idx = PADI(base + m*S);
        sre[idx] = o.x; sim[idx] = o.y;
      }
    } else {
      #pragma unroll
      for (int p = 0; p < 8; ++p) {
        const int m = BR3[p];
        int idx = PADI(base + m*S);
        cplx v = {sre[idx], sim[idx]};
        a[p] = cmul(v, wp[m]);
      }
      fft_regs<8,true>(a);
      #pragma unroll
      for (int j = 0; j < 8; ++j) { int idx = PADI(base + j*S); sre[idx] = a[j].x; sim[idx] = a[j].y; }
    }
  }
}

// LDS radix-8 stage, S = 4 (M = 32). 2048 butterflies; B = 2048/NT per thread.
// NT=512: thread owns subproblem q=tid (r=0..3). NT=1024: 2 threads per
// subproblem, q=tid>>1, r=(tid&1)*2+rr. Bank aliasing stays 2-way = free.
template<int NT, bool INV>
__device__ __forceinline__ void stage8_s4(float* sre, float* sim, int tid) {
  constexpr int B = 2048 / NT;
  const float ang1 = (INV ? 2.0f : -2.0f) * 3.14159265358979f / 32.0f;
  int q, r0;
  if constexpr (NT == 512) { q = tid;      r0 = 0; }
  else                     { q = tid >> 1; r0 = (tid & 1) * B; }
  #pragma unroll
  for (int rr = 0; rr < B; ++rr) {
    int r = r0 + rr;
    int base = q * 32 + r;
    float t = ang1 * (float)r;
    cplx w1 = {__cosf(t), __sinf(t)};
    cplx wp[8];
    wp[0] = {1.0f, 0.0f};
    #pragma unroll
    for (int m = 1; m < 8; ++m) wp[m] = cmul(wp[m-1], w1);

    cplx a[8];
    if (!INV) {
      #pragma unroll
      for (int j = 0; j < 8; ++j) { int idx = PADI(base + j*4); a[j] = {sre[idx], sim[idx]}; }
      fft_regs<8,false>(a);
      #pragma unroll
      for (int p = 0; p < 8; ++p) {
        const int m = BR3[p];
        cplx o = cmul(a[p], wp[m]);
        int idx = PADI(base + m*4);
        sre[idx] = o.x; sim[idx] = o.y;
      }
    } else {
      #pragma unroll
      for (int p = 0; p < 8; ++p) {
        const int m = BR3[p];
        int idx = PADI(base + m*4);
        cplx v = {sre[idx], sim[idx]};
        a[p] = cmul(v, wp[m]);
      }
      fft_regs<8,true>(a);
      #pragma unroll
      for (int j = 0; j < 8; ++j) { int idx = PADI(base + j*4); sre[idx] = a[j].x; sim[idx] = a[j].y; }
    }
  }
}

// ---------- kernel 1: K-spectrum precompute into d_ws (scrambled order) -----
__global__ __launch_bounds__(NTH)
void kfft_kernel(const float* __restrict__ kin, float2* __restrict__ kh) {
  __shared__ float sre[LDSN];
  __shared__ float sim[LDSN];
  const int tid = threadIdx.x;
  const int h = blockIdx.x;
  const float* krow = kin + (size_t)h * LSIG;
  #pragma unroll
  for (int c = 0; c < LSIG/(NTH*4); ++c) {
    int i0 = (c * NTH + tid) * 4;
    float4 v = *reinterpret_cast<const float4*>(krow + i0);
    int p0 = PADI(i0);
    sre[p0+0]=v.x; sre[p0+1]=v.y; sre[p0+2]=v.z; sre[p0+3]=v.w;
    sim[p0+0]=0.f; sim[p0+1]=0.f; sim[p0+2]=0.f; sim[p0+3]=0.f;
    int p1 = PADI(i0 + LSIG);
    sre[p1+0]=0.f; sre[p1+1]=0.f; sre[p1+2]=0.f; sre[p1+3]=0.f;
    sim[p1+0]=0.f; sim[p1+1]=0.f; sim[p1+2]=0.f; sim[p1+3]=0.f;
  }
  __syncthreads();
  stage8<NTH,2048,false>(sre, sim, tid); __syncthreads();
  stage8<NTH, 256,false>(sre, sim, tid); __syncthreads();
  stage8<NTH,  32,false>(sre, sim, tid); __syncthreads();
  stage8_s4<NTH,false>(sre, sim, tid);   __syncthreads();

  const float scl = 1.0f / (float)NFFT;
  float2* row = kh + (size_t)h * NFFT;
  #pragma unroll
  for (int s = 0; s < NFFT/4/NTH; ++s) {
    int m = tid + NTH * s;
    int i0 = 4 * m;
    int p = PADI(i0);
    cplx z[4] = { {sre[p+0], sim[p+0]}, {sre[p+1], sim[p+1]},
                  {sre[p+2], sim[p+2]}, {sre[p+3], sim[p+3]} };
    fft_regs<4,false>(z);
    #pragma unroll
    for (int e = 0; e < 4; ++e) row[i0+e] = make_float2(z[e].x*scl, z[e].y*scl);
  }
}

// ---------- kernel 2: conv, 1024 threads -> 16 waves/CU (4/SIMD) ------------
__global__ __launch_bounds__(NTH)
void conv_kernel(const float* __restrict__ u, const float2* __restrict__ kh,
                 float* __restrict__ out) {
  __shared__ float sre[LDSN];
  __shared__ float sim[LDSN];
  const int tid = threadIdx.x;
  const int bid = blockIdx.x;
  const int h  = bid >> 2;          // 4 same-h blocks temporally adjacent
  const int pr = bid & 3;

  const float* u0 = u + ((size_t)(2*pr) * NH + h) * LSIG;
  const float* u1 = u0 + (size_t)NH * LSIG;
  #pragma unroll
  for (int c = 0; c < LSIG/(NTH*4); ++c) {
    int i0 = (c * NTH + tid) * 4;
    float4 a = *reinterpret_cast<const float4*>(u0 + i0);
    float4 b = *reinterpret_cast<const float4*>(u1 + i0);
    int p0 = PADI(i0);
    sre[p0+0]=a.x; sre[p0+1]=a.y; sre[p0+2]=a.z; sre[p0+3]=a.w;
    sim[p0+0]=b.x; sim[p0+1]=b.y; sim[p0+2]=b.z; sim[p0+3]=b.w;
    int p1 = PADI(i0 + LSIG);
    sre[p1+0]=0.f; sre[p1+1]=0.f; sre[p1+2]=0.f; sre[p1+3]=0.f;
    sim[p1+0]=0.f; sim[p1+1]=0.f; sim[p1+2]=0.f; sim[p1+3]=0.f;
  }
  __syncthreads();
  stage8<NTH,2048,false>(sre, sim, tid); __syncthreads();
  stage8<NTH, 256,false>(sre, sim, tid); __syncthreads();
  stage8<NTH,  32,false>(sre, sim, tid); __syncthreads();
  stage8_s4<NTH,false>(sre, sim, tid);   __syncthreads();

  {   // fused per-quad: DFT4 -> multiply K-hat -> inverse DFT4
    const float2* krow = kh + (size_t)h * NFFT;
    #pragma unroll
    for (int s = 0; s < NFFT/4/NTH; ++s) {
      int m = tid + NTH * s;
      int i0 = 4 * m;
      int p = PADI(i0);
      cplx z[4] = { {sre[p+0], sim[p+0]}, {sre[p+1], sim[p+1]},
                    {sre[p+2], sim[p+2]}, {sre[p+3], sim[p+3]} };
      fft_regs<4,false>(z);
      float4 k0 = *reinterpret_cast<const float4*>(krow + i0 + 0);
      float4 k1 = *reinterpret_cast<const float4*>(krow + i0 + 2);
      z[0] = cmul(z[0], cplx{k0.x, k0.y});
      z[1] = cmul(z[1], cplx{k0.z, k0.w});
      z[2] = cmul(z[2], cplx{k1.x, k1.y});
      z[3] = cmul(z[3], cplx{k1.z, k1.w});
      fft_regs<4,true>(z);
      #pragma unroll
      for (int e = 0; e < 4; ++e) { sre[p+e] = z[e].x; sim[p+e] = z[e].y; }
    }
  }
  __syncthreads();
  stage8_s4<NTH,true>(sre, sim, tid);   __syncthreads();
  stage8<NTH,  32,true>(sre, sim, tid); __syncthreads();
  stage8<NTH, 256,true>(sre, sim, tid); __syncthreads();
  stage8<NTH,2048,true>(sre, sim, tid); __syncthreads();

  float* o0 = out + ((size_t)(2*pr) * NH + h) * LSIG;
  float* o1 = o0 + (size_t)NH * LSIG;
  #pragma unroll
  for (int c = 0; c < LSIG/(NTH*4); ++c) {
    int i0 = (c * NTH + tid) * 4;
    int p0 = PADI(i0);
    float4 a = {sre[p0], sre[p0+1], sre[p0+2], sre[p0+3]};
    float4 b = {sim[p0], sim[p0+1], sim[p0+2], sim[p0+3]};
    *reinterpret_cast<float4*>(o0 + i0) = a;
    *reinterpret_cast<float4*>(o1 + i0) = b;
  }
}

// ---------- fallback (monolithic 512-thread, known-good) if ws too small ----
__global__ __launch_bounds__(FTH)
void fftconv_fallback(const float* __restrict__ u, const float* __restrict__ kin,
                      float* __restrict__ out) {
  __shared__ float sre[LDSN];
  __shared__ float sim[LDSN];
  const int tid = threadIdx.x;
  const int bid = blockIdx.x;
  const int h  = bid >> 2;
  const int pr = bid & 3;

  const float* krow = kin + (size_t)h * LSIG;
  #pragma unroll
  for (int c = 0; c < LSIG/(FTH*4); ++c) {
    int i0 = (c * FTH + tid) * 4;
    float4 v = *reinterpret_cast<const float4*>(krow + i0);
    int p0 = PADI(i0);
    sre[p0+0]=v.x; sre[p0+1]=v.y; sre[p0+2]=v.z; sre[p0+3]=v.w;
    sim[p0+0]=0.f; sim[p0+1]=0.f; sim[p0+2]=0.f; sim[p0+3]=0.f;
    int p1 = PADI(i0 + LSIG);
    sre[p1+0]=0.f; sre[p1+1]=0.f; sre[p1+2]=0.f; sre[p1+3]=0.f;
    sim[p1+0]=0.f; sim[p1+1]=0.f; sim[p1+2]=0.f; sim[p1+3]=0.f;
  }
  __syncthreads();
  stage8<FTH,2048,false>(sre, sim, tid); __syncthreads();
  stage8<FTH, 256,false>(sre, sim, tid); __syncthreads();
  stage8<FTH,  32,false>(sre, sim, tid); __syncthreads();
  stage8_s4<FTH,false>(sre, sim, tid);   __syncthreads();

  cplx kq[4][4];
  cplx kq2[4][4];
  const float scl = 1.0f / (float)NFFT;
  #pragma unroll
  for (int s = 0; s < 8; ++s) {
    int m = tid + FTH * s;
    int p = PADI(4 * m);
    cplx z[4] = { {sre[p+0], sim[p+0]}, {sre[p+1], sim[p+1]},
                  {sre[p+2], sim[p+2]}, {sre[p+3], sim[p+3]} };
    fft_regs<4,false>(z);
    #pragma unroll
    for (int e = 0; e < 4; ++e) {
      cplx v = {z[e].x*scl, z[e].y*scl};
      if (s < 4) kq[s][e] = v; else kq2[s-4][e] = v;
    }
  }
  __syncthreads();

  const float* u0 = u + ((size_t)(2*pr) * NH + h) * LSIG;
  const float* u1 = u0 + (size_t)NH * LSIG;
  #pragma unroll
  for (int c = 0; c < LSIG/(FTH*4); ++c) {
    int i0 = (c * FTH + tid) * 4;
    float4 a = *reinterpret_cast<const float4*>(u0 + i0);
    float4 b = *reinterpret_cast<const float4*>(u1 + i0);
    int p0 = PADI(i0);
    sre[p0+0]=a.x; sre[p0+1]=a.y; sre[p0+2]=a.z; sre[p0+3]=a.w;
    sim[p0+0]=b.x; sim[p0+1]=b.y; sim[p0+2]=b.z; sim[p0+3]=b.w;
    int p1 = PADI(i0 + LSIG);
    sre[p1+0]=0.f; sre[p1+1]=0.f; sre[p1+2]=0.f; sre[p1+3]=0.f;
    sim[p1+0]=0.f; sim[p1+1]=0.f; sim[p1+2]=0.f; sim[p1+3]=0.f;
  }
  __syncthreads();
  stage8<FTH,2048,false>(sre, sim, tid); __syncthreads();
  stage8<FTH, 256,false>(sre, sim, tid); __syncthreads();
  stage8<FTH,  32,false>(sre, sim, tid); __syncthreads();
  stage8_s4<FTH,false>(sre, sim, tid);   __syncthreads();

  #pragma unroll
  for (int s = 0; s < 8; ++s) {
    int m = tid + FTH * s;
    int p = PADI(4 * m);
    cplx z[4] = { {sre[p+0], sim[p+0]}, {sre[p+1], sim[p+1]},
                  {sre[p+2], sim[p+2]}, {sre[p+3], sim[p+3]} };
    fft_regs<4,false>(z);
    #pragma unroll
    for (int e = 0; e < 4; ++e) z[e] = cmul(z[e], (s<4) ? kq[s][e] : kq2[s-4][e]);
    fft_regs<4,true>(z);
    #pragma unroll
    for (int e = 0; e < 4; ++e) { sre[p+e] = z[e].x; sim[p+e] = z[e].y; }
  }
  __syncthreads();
  stage8_s4<FTH,true>(sre, sim, tid);   __syncthreads();
  stage8<FTH,  32,true>(sre, sim, tid); __syncthreads();
  stage8<FTH, 256,true>(sre, sim, tid); __syncthreads();
  stage8<FTH,2048,true>(sre, sim, tid); __syncthreads();

  float* o0 = out + ((size_t)(2*pr) * NH + h) * LSIG;
  float* o1 = o0 + (size_t)NH * LSIG;
  #pragma unroll
  for (int c = 0; c < LSIG/(FTH*4); ++c) {
    int i0 = (c * FTH + tid) * 4;
    int p0 = PADI(i0);
    float4 a = {sre[p0], sre[p0+1], sre[p0+2], sre[p0+3]};
    float4 b = {sim[p0], sim[p0+1], sim[p0+2], sim[p0+3]};
    *reinterpret_cast<float4*>(o0 + i0) = a;
    *reinterpret_cast<float4*>(o1 + i0) = b;
  }
}

extern "C" void kernel_launch(void* const* d_in, const int* in_sizes, int n_in,
                              void* d_out, int out_size, void* d_ws, size_t ws_size,
                              hipStream_t stream) {
  (void)in_sizes; (void)n_in; (void)out_size;
  const float* u = (const float*)d_in[0];
  const float* k = (const float*)d_in[1];
  float* out = (float*)d_out;
  const size_t need = (size_t)NH * NFFT * sizeof(float2);   // 128 MiB
  if (ws_size >= need) {
    hipLaunchKernelGGL(kfft_kernel, dim3(NH),   dim3(NTH), 0, stream, k, (float2*)d_ws);
    hipLaunchKernelGGL(conv_kernel, dim3(4096), dim3(NTH), 0, stream, u, (const float2*)d_ws, out);
  } else {
    hipLaunchKernelGGL(fftconv_fallback, dim3(4096), dim3(FTH), 0, stream, u, k, out);
  }
}

// Round 9
// 513.769 us; speedup vs baseline: 1.1854x; 1.1854x over previous
//
#include <hip/hip_runtime.h>

#define NFFT 16384
#define LSIG 8192
#define NH   1024
#define NTH  512
#define LDSN (NFFT + (NFFT >> 5))   // pad every 32 floats

__device__ __forceinline__ int PADI(int i) { return i + (i >> 5); }

struct cplx { float x, y; };
__device__ __forceinline__ cplx cadd(cplx a, cplx b){ return {a.x+b.x, a.y+b.y}; }
__device__ __forceinline__ cplx csub(cplx a, cplx b){ return {a.x-b.x, a.y-b.y}; }
__device__ __forceinline__ cplx cmul(cplx a, cplx b){ return {a.x*b.x - a.y*b.y, a.x*b.y + a.y*b.x}; }

// compile-time for: cfor<0,N>([&](auto ic){ constexpr int i = decltype(ic)::value; ... });
template<int V> struct ic { static constexpr int value = V; };
template<int Start, int End, typename F>
__device__ __forceinline__ void cfor(F&& f) {
  if constexpr (Start < End) { f(ic<Start>{}); cfor<Start+1, End>(static_cast<F&&>(f)); }
}

// Full-period W32 tables (cos/sin of 2*pi*k/32, k=0..31) — compile-time only.
constexpr float W32C32[32] = {
  1.0f, 0.9807852804f, 0.9238795325f, 0.8314696123f,
  0.7071067812f, 0.5555702330f, 0.3826834324f, 0.1950903220f,
  0.0f, -0.1950903220f, -0.3826834324f, -0.5555702330f,
  -0.7071067812f, -0.8314696123f, -0.9238795325f, -0.9807852804f,
  -1.0f, -0.9807852804f, -0.9238795325f, -0.8314696123f,
  -0.7071067812f, -0.5555702330f, -0.3826834324f, -0.1950903220f,
  0.0f, 0.1950903220f, 0.3826834324f, 0.5555702330f,
  0.7071067812f, 0.8314696123f, 0.9238795325f, 0.9807852804f };
constexpr float W32S32[32] = {
  0.0f, 0.1950903220f, 0.3826834324f, 0.5555702330f,
  0.7071067812f, 0.8314696123f, 0.9238795325f, 0.9807852804f,
  1.0f, 0.9807852804f, 0.9238795325f, 0.8314696123f,
  0.7071067812f, 0.5555702330f, 0.3826834324f, 0.1950903220f,
  0.0f, -0.1950903220f, -0.3826834324f, -0.5555702330f,
  -0.7071067812f, -0.8314696123f, -0.9238795325f, -0.9807852804f,
  -1.0f, -0.9807852804f, -0.9238795325f, -0.8314696123f,
  -0.7071067812f, -0.5555702330f, -0.3826834324f, -0.1950903220f };
constexpr int BR3[8] = {0,4,2,6,1,5,3,7};

// d * W32^KK (fwd = conjugate twiddle, inv = plain). Trivial angles cost 0-2 ops.
template<int KK, bool INV>
__device__ __forceinline__ cplx twid(cplx d) {
  constexpr int K = KK & 31;
  if constexpr (K == 0)       return d;
  else if constexpr (K == 8)  { if constexpr (INV) return cplx{-d.y, d.x}; else return cplx{d.y, -d.x}; }
  else if constexpr (K == 16) return cplx{-d.x, -d.y};
  else if constexpr (K == 24) { if constexpr (INV) return cplx{d.y, -d.x}; else return cplx{-d.y, d.x}; }
  else {
    constexpr float c = W32C32[K];
    constexpr float s = INV ? W32S32[K] : -W32S32[K];
    return cmul(d, cplx{c, s});
  }
}

// Radix-2 pass, compile-time span SP; twiddles via twid<> (trivial ones free).
template<int N, int SP, bool INV>
__device__ __forceinline__ void fft_pass(cplx* z) {
  #pragma unroll
  for (int b = 0; b < N; b += 2*SP) {
    cfor<0, SP>([&](auto rc){
      constexpr int r = decltype(rc)::value;
      constexpr int KK = r * (16 / SP);       // W_{2SP}^r = W32^KK
      if constexpr (!INV) {
        cplx u = z[b+r], v = z[b+r+SP];
        z[b+r]    = cadd(u, v);
        z[b+r+SP] = twid<KK,false>(csub(u, v));
      } else {
        cplx t0 = z[b+r], t1 = z[b+r+SP];
        cplx w = twid<KK,true>(t1);
        z[b+r]    = cadd(t0, w);
        z[b+r+SP] = csub(t0, w);
      }
    });
  }
}

template<int N, bool INV>
__device__ __forceinline__ void fft_regs(cplx* z) {
  if constexpr (!INV) {
    if constexpr (N >= 32) fft_pass<N,16,false>(z);
    if constexpr (N >= 16) fft_pass<N, 8,false>(z);
    if constexpr (N >=  8) fft_pass<N, 4,false>(z);
    if constexpr (N >=  4) fft_pass<N, 2,false>(z);
    fft_pass<N,1,false>(z);
  } else {
    fft_pass<N,1,true>(z);
    if constexpr (N >=  4) fft_pass<N, 2,true>(z);
    if constexpr (N >=  8) fft_pass<N, 4,true>(z);
    if constexpr (N >= 16) fft_pass<N, 8,true>(z);
    if constexpr (N >= 32) fft_pass<N,16,true>(z);
  }
}

// LDS radix-8 stage, S >= 32. Runtime twiddle base via sincos; wp chain is
// log-depth (3 deep, was 7); m==0 output multiply skipped.
template<int S, bool INV>
__device__ __forceinline__ void stage8(float* sre, float* sim, int tid) {
  const float ang1 = (INV ? 2.0f : -2.0f) * 3.14159265358979f / (float)(8 * S);
  #pragma unroll
  for (int it = 0; it < (NFFT/8)/NTH; ++it) {
    int bf = tid + it * NTH;
    int q = bf / S;
    int r = bf - q * S;
    int base = q * (8 * S) + r;
    float t = ang1 * (float)r;
    cplx w1 = {__cosf(t), __sinf(t)};
    cplx wp[8];
    wp[0] = {1.0f, 0.0f};
    wp[1] = w1;
    wp[2] = cmul(w1, w1);
    wp[3] = cmul(wp[2], w1);
    wp[4] = cmul(wp[2], wp[2]);
    wp[5] = cmul(wp[4], wp[1]);
    wp[6] = cmul(wp[4], wp[2]);
    wp[7] = cmul(wp[4], wp[3]);

    cplx a[8];
    if constexpr (!INV) {
      cfor<0,8>([&](auto jc){ constexpr int j = decltype(jc)::value;
        int idx = PADI(base + j*S); a[j] = {sre[idx], sim[idx]}; });
      fft_regs<8,false>(a);
      cfor<0,8>([&](auto pc){ constexpr int p = decltype(pc)::value;
        constexpr int m = BR3[p];
        cplx o;
        if constexpr (m == 0) o = a[p]; else o = cmul(a[p], wp[m]);
        int idx = PADI(base + m*S);
        sre[idx] = o.x; sim[idx] = o.y; });
    } else {
      cfor<0,8>([&](auto pc){ constexpr int p = decltype(pc)::value;
        constexpr int m = BR3[p];
        int idx = PADI(base + m*S);
        cplx v = {sre[idx], sim[idx]};
        if constexpr (m == 0) a[p] = v; else a[p] = cmul(v, wp[m]);  });
      fft_regs<8,true>(a);
      cfor<0,8>([&](auto jc){ constexpr int j = decltype(jc)::value;
        int idx = PADI(base + j*S); sre[idx] = a[j].x; sim[idx] = a[j].y; });
    }
  }
}

// LDS radix-8 stage, S = 4 (M = 32). Thread owns subproblem q = tid, r is
// COMPILE-TIME -> every twiddle W32^(r*m) is a literal constant (no trans,
// no chain). 2-way bank aliasing = free.
template<bool INV>
__device__ __forceinline__ void stage8_s4(float* sre, float* sim, int tid) {
  cfor<0,4>([&](auto rc){
    constexpr int r = decltype(rc)::value;
    int base = tid * 32 + r;
    cplx a[8];
    if constexpr (!INV) {
      cfor<0,8>([&](auto jc){ constexpr int j = decltype(jc)::value;
        int idx = PADI(base + j*4); a[j] = {sre[idx], sim[idx]}; });
      fft_regs<8,false>(a);
      cfor<0,8>([&](auto pc){ constexpr int p = decltype(pc)::value;
        constexpr int m = BR3[p];
        cplx o = twid<r*m, false>(a[p]);
        int idx = PADI(base + m*4);
        sre[idx] = o.x; sim[idx] = o.y; });
    } else {
      cfor<0,8>([&](auto pc){ constexpr int p = decltype(pc)::value;
        constexpr int m = BR3[p];
        int idx = PADI(base + m*4);
        cplx v = {sre[idx], sim[idx]};
        a[p] = twid<r*m, true>(v); });
      fft_regs<8,true>(a);
      cfor<0,8>([&](auto jc){ constexpr int j = decltype(jc)::value;
        int idx = PADI(base + j*4); sre[idx] = a[j].x; sim[idx] = a[j].y; });
    }
  });
}

// ---------- kernel 1: K-spectrum precompute into d_ws (scrambled order) -----
__global__ __launch_bounds__(NTH)
void kfft_kernel(const float* __restrict__ kin, float2* __restrict__ kh) {
  __shared__ float sre[LDSN];
  __shared__ float sim[LDSN];
  const int tid = threadIdx.x;
  const int h = blockIdx.x;
  const float* krow = kin + (size_t)h * LSIG;
  #pragma unroll
  for (int c = 0; c < 4; ++c) {
    int i0 = (c * NTH + tid) * 4;
    float4 v = *reinterpret_cast<const float4*>(krow + i0);
    int p0 = PADI(i0);
    sre[p0+0]=v.x; sre[p0+1]=v.y; sre[p0+2]=v.z; sre[p0+3]=v.w;
    sim[p0+0]=0.f; sim[p0+1]=0.f; sim[p0+2]=0.f; sim[p0+3]=0.f;
    int p1 = PADI(i0 + LSIG);
    sre[p1+0]=0.f; sre[p1+1]=0.f; sre[p1+2]=0.f; sre[p1+3]=0.f;
    sim[p1+0]=0.f; sim[p1+1]=0.f; sim[p1+2]=0.f; sim[p1+3]=0.f;
  }
  __syncthreads();
  stage8<2048,false>(sre, sim, tid); __syncthreads();
  stage8< 256,false>(sre, sim, tid); __syncthreads();
  stage8<  32,false>(sre, sim, tid); __syncthreads();
  stage8_s4<false>(sre, sim, tid);   __syncthreads();

  const float scl = 1.0f / (float)NFFT;
  float2* row = kh + (size_t)h * NFFT;
  #pragma unroll
  for (int s = 0; s < 8; ++s) {
    int m = tid + NTH * s;
    int i0 = 4 * m;
    int p = PADI(i0);
    cplx z[4] = { {sre[p+0], sim[p+0]}, {sre[p+1], sim[p+1]},
                  {sre[p+2], sim[p+2]}, {sre[p+3], sim[p+3]} };
    fft_regs<4,false>(z);
    #pragma unroll
    for (int e = 0; e < 4; ++e) row[i0+e] = make_float2(z[e].x*scl, z[e].y*scl);
  }
}

// ---------- kernel 2: conv (round-7 structure, 512 threads, no spill) -------
__global__ __launch_bounds__(NTH)
void conv_kernel(const float* __restrict__ u, const float2* __restrict__ kh,
                 float* __restrict__ out) {
  __shared__ float sre[LDSN];
  __shared__ float sim[LDSN];
  const int tid = threadIdx.x;
  const int bid = blockIdx.x;
  const int h  = bid >> 2;          // 4 same-h blocks temporally adjacent
  const int pr = bid & 3;

  const float* u0 = u + ((size_t)(2*pr) * NH + h) * LSIG;
  const float* u1 = u0 + (size_t)NH * LSIG;
  #pragma unroll
  for (int c = 0; c < 4; ++c) {
    int i0 = (c * NTH + tid) * 4;
    float4 a = *reinterpret_cast<const float4*>(u0 + i0);
    float4 b = *reinterpret_cast<const float4*>(u1 + i0);
    int p0 = PADI(i0);
    sre[p0+0]=a.x; sre[p0+1]=a.y; sre[p0+2]=a.z; sre[p0+3]=a.w;
    sim[p0+0]=b.x; sim[p0+1]=b.y; sim[p0+2]=b.z; sim[p0+3]=b.w;
    int p1 = PADI(i0 + LSIG);
    sre[p1+0]=0.f; sre[p1+1]=0.f; sre[p1+2]=0.f; sre[p1+3]=0.f;
    sim[p1+0]=0.f; sim[p1+1]=0.f; sim[p1+2]=0.f; sim[p1+3]=0.f;
  }
  __syncthreads();
  stage8<2048,false>(sre, sim, tid); __syncthreads();
  stage8< 256,false>(sre, sim, tid); __syncthreads();
  stage8<  32,false>(sre, sim, tid); __syncthreads();
  stage8_s4<false>(sre, sim, tid);   __syncthreads();

  {   // fused per-quad: DFT4 -> multiply K-hat -> inverse DFT4
    const float2* krow = kh + (size_t)h * NFFT;
    #pragma unroll
    for (int s = 0; s < 8; ++s) {
      int m = tid + NTH * s;
      int i0 = 4 * m;
      int p = PADI(i0);
      cplx z[4] = { {sre[p+0], sim[p+0]}, {sre[p+1], sim[p+1]},
                    {sre[p+2], sim[p+2]}, {sre[p+3], sim[p+3]} };
      fft_regs<4,false>(z);
      float4 k0 = *reinterpret_cast<const float4*>(krow + i0 + 0);
      float4 k1 = *reinterpret_cast<const float4*>(krow + i0 + 2);
      z[0] = cmul(z[0], cplx{k0.x, k0.y});
      z[1] = cmul(z[1], cplx{k0.z, k0.w});
      z[2] = cmul(z[2], cplx{k1.x, k1.y});
      z[3] = cmul(z[3], cplx{k1.z, k1.w});
      fft_regs<4,true>(z);
      #pragma unroll
      for (int e = 0; e < 4; ++e) { sre[p+e] = z[e].x; sim[p+e] = z[e].y; }
    }
  }
  __syncthreads();
  stage8_s4<true>(sre, sim, tid);   __syncthreads();
  stage8<  32,true>(sre, sim, tid); __syncthreads();
  stage8< 256,true>(sre, sim, tid); __syncthreads();
  stage8<2048,true>(sre, sim, tid); __syncthreads();

  float* o0 = out + ((size_t)(2*pr) * NH + h) * LSIG;
  float* o1 = o0 + (size_t)NH * LSIG;
  #pragma unroll
  for (int c = 0; c < 4; ++c) {
    int i0 = (c * NTH + tid) * 4;
    int p0 = PADI(i0);
    float4 a = {sre[p0], sre[p0+1], sre[p0+2], sre[p0+3]};
    float4 b = {sim[p0], sim[p0+1], sim[p0+2], sim[p0+3]};
    *reinterpret_cast<float4*>(o0 + i0) = a;
    *reinterpret_cast<float4*>(o1 + i0) = b;
  }
}

// ---------- fallback (monolithic, known-good) if ws too small ---------------
__global__ __launch_bounds__(NTH)
void fftconv_fallback(const float* __restrict__ u, const float* __restrict__ kin,
                      float* __restrict__ out) {
  __shared__ float sre[LDSN];
  __shared__ float sim[LDSN];
  const int tid = threadIdx.x;
  const int bid = blockIdx.x;
  const int h  = bid >> 2;
  const int pr = bid & 3;

  const float* krow = kin + (size_t)h * LSIG;
  #pragma unroll
  for (int c = 0; c < 4; ++c) {
    int i0 = (c * NTH + tid) * 4;
    float4 v = *reinterpret_cast<const float4*>(krow + i0);
    int p0 = PADI(i0);
    sre[p0+0]=v.x; sre[p0+1]=v.y; sre[p0+2]=v.z; sre[p0+3]=v.w;
    sim[p0+0]=0.f; sim[p0+1]=0.f; sim[p0+2]=0.f; sim[p0+3]=0.f;
    int p1 = PADI(i0 + LSIG);
    sre[p1+0]=0.f; sre[p1+1]=0.f; sre[p1+2]=0.f; sre[p1+3]=0.f;
    sim[p1+0]=0.f; sim[p1+1]=0.f; sim[p1+2]=0.f; sim[p1+3]=0.f;
  }
  __syncthreads();
  stage8<2048,false>(sre, sim, tid); __syncthreads();
  stage8< 256,false>(sre, sim, tid); __syncthreads();
  stage8<  32,false>(sre, sim, tid); __syncthreads();
  stage8_s4<false>(sre, sim, tid);   __syncthreads();

  cplx kq[4][4];
  cplx kq2[4][4];
  const float scl = 1.0f / (float)NFFT;
  #pragma unroll
  for (int s = 0; s < 8; ++s) {
    int m = tid + NTH * s;
    int p = PADI(4 * m);
    cplx z[4] = { {sre[p+0], sim[p+0]}, {sre[p+1], sim[p+1]},
                  {sre[p+2], sim[p+2]}, {sre[p+3], sim[p+3]} };
    fft_regs<4,false>(z);
    #pragma unroll
    for (int e = 0; e < 4; ++e) {
      cplx v = {z[e].x*scl, z[e].y*scl};
      if (s < 4) kq[s][e] = v; else kq2[s-4][e] = v;
    }
  }
  __syncthreads();

  const float* u0 = u + ((size_t)(2*pr) * NH + h) * LSIG;
  const float* u1 = u0 + (size_t)NH * LSIG;
  #pragma unroll
  for (int c = 0; c < 4; ++c) {
    int i0 = (c * NTH + tid) * 4;
    float4 a = *reinterpret_cast<const float4*>(u0 + i0);
    float4 b = *reinterpret_cast<const float4*>(u1 + i0);
    int p0 = PADI(i0);
    sre[p0+0]=a.x; sre[p0+1]=a.y; sre[p0+2]=a.z; sre[p0+3]=a.w;
    sim[p0+0]=b.x; sim[p0+1]=b.y; sim[p0+2]=b.z; sim[p0+3]=b.w;
    int p1 = PADI(i0 + LSIG);
    sre[p1+0]=0.f; sre[p1+1]=0.f; sre[p1+2]=0.f; sre[p1+3]=0.f;
    sim[p1+0]=0.f; sim[p1+1]=0.f; sim[p1+2]=0.f; sim[p1+3]=0.f;
  }
  __syncthreads();
  stage8<2048,false>(sre, sim, tid); __syncthreads();
  stage8< 256,false>(sre, sim, tid); __syncthreads();
  stage8<  32,false>(sre, sim, tid); __syncthreads();
  stage8_s4<false>(sre, sim, tid);   __syncthreads();

  #pragma unroll
  for (int s = 0; s < 8; ++s) {
    int m = tid + NTH * s;
    int p = PADI(4 * m);
    cplx z[4] = { {sre[p+0], sim[p+0]}, {sre[p+1], sim[p+1]},
                  {sre[p+2], sim[p+2]}, {sre[p+3], sim[p+3]} };
    fft_regs<4,false>(z);
    #pragma unroll
    for (int e = 0; e < 4; ++e) z[e] = cmul(z[e], (s<4) ? kq[s][e] : kq2[s-4][e]);
    fft_regs<4,true>(z);
    #pragma unroll
    for (int e = 0; e < 4; ++e) { sre[p+e] = z[e].x; sim[p+e] = z[e].y; }
  }
  __syncthreads();
  stage8_s4<true>(sre, sim, tid);   __syncthreads();
  stage8<  32,true>(sre, sim, tid); __syncthreads();
  stage8< 256,true>(sre, sim, tid); __syncthreads();
  stage8<2048,true>(sre, sim, tid); __syncthreads();

  float* o0 = out + ((size_t)(2*pr) * NH + h) * LSIG;
  float* o1 = o0 + (size_t)NH * LSIG;
  #pragma unroll
  for (int c = 0; c < 4; ++c) {
    int i0 = (c * NTH + tid) * 4;
    int p0 = PADI(i0);
    float4 a = {sre[p0], sre[p0+1], sre[p0+2], sre[p0+3]};
    float4 b = {sim[p0], sim[p0+1], sim[p0+2], sim[p0+3]};
    *reinterpret_cast<float4*>(o0 + i0) = a;
    *reinterpret_cast<float4*>(o1 + i0) = b;
  }
}

extern "C" void kernel_launch(void* const* d_in, const int* in_sizes, int n_in,
                              void* d_out, int out_size, void* d_ws, size_t ws_size,
                              hipStream_t stream) {
  (void)in_sizes; (void)n_in; (void)out_size;
  const float* u = (const float*)d_in[0];
  const float* k = (const float*)d_in[1];
  float* out = (float*)d_out;
  const size_t need = (size_t)NH * NFFT * sizeof(float2);   // 128 MiB
  if (ws_size >= need) {
    hipLaunchKernelGGL(kfft_kernel, dim3(NH),   dim3(NTH), 0, stream, k, (float2*)d_ws);
    hipLaunchKernelGGL(conv_kernel, dim3(4096), dim3(NTH), 0, stream, u, (const float2*)d_ws, out);
  } else {
    hipLaunchKernelGGL(fftconv_fallback, dim3(4096), dim3(NTH), 0, stream, u, k, out);
  }
}

// Round 10
// 444.591 us; speedup vs baseline: 1.3698x; 1.1556x over previous
//
#include <hip/hip_runtime.h>

#define NFFT 16384
#define LSIG 8192
#define NH   1024
#define NTH  512
// float2 (interleaved re/im) LDS plane; pad 2 complexes per 32 so that every
// even complex index stays 16B-aligned after padding (b128-safe).
#define LDSC (NFFT + ((NFFT >> 5) << 1))   // 17408 complexes = 139264 B

__device__ __forceinline__ int PADC(int i) { return i + ((i >> 5) << 1); }
__device__ __forceinline__ int PADI(int i) { return i + (i >> 5); }   // old scalar layout (fallback)

struct cplx { float x, y; };
__device__ __forceinline__ cplx cadd(cplx a, cplx b){ return {a.x+b.x, a.y+b.y}; }
__device__ __forceinline__ cplx csub(cplx a, cplx b){ return {a.x-b.x, a.y-b.y}; }
__device__ __forceinline__ cplx cmul(cplx a, cplx b){ return {a.x*b.x - a.y*b.y, a.x*b.y + a.y*b.x}; }

template<int V> struct ic { static constexpr int value = V; };
template<int Start, int End, typename F>
__device__ __forceinline__ void cfor(F&& f) {
  if constexpr (Start < End) { f(ic<Start>{}); cfor<Start+1, End>(static_cast<F&&>(f)); }
}

constexpr float W32C32[32] = {
  1.0f, 0.9807852804f, 0.9238795325f, 0.8314696123f,
  0.7071067812f, 0.5555702330f, 0.3826834324f, 0.1950903220f,
  0.0f, -0.1950903220f, -0.3826834324f, -0.5555702330f,
  -0.7071067812f, -0.8314696123f, -0.9238795325f, -0.9807852804f,
  -1.0f, -0.9807852804f, -0.9238795325f, -0.8314696123f,
  -0.7071067812f, -0.5555702330f, -0.3826834324f, -0.1950903220f,
  0.0f, 0.1950903220f, 0.3826834324f, 0.5555702330f,
  0.7071067812f, 0.8314696123f, 0.9238795325f, 0.9807852804f };
constexpr float W32S32[32] = {
  0.0f, 0.1950903220f, 0.3826834324f, 0.5555702330f,
  0.7071067812f, 0.8314696123f, 0.9238795325f, 0.9807852804f,
  1.0f, 0.9807852804f, 0.9238795325f, 0.8314696123f,
  0.7071067812f, 0.5555702330f, 0.3826834324f, 0.1950903220f,
  0.0f, -0.1950903220f, -0.3826834324f, -0.5555702330f,
  -0.7071067812f, -0.8314696123f, -0.9238795325f, -0.9807852804f,
  -1.0f, -0.9807852804f, -0.9238795325f, -0.8314696123f,
  -0.7071067812f, -0.5555702330f, -0.3826834324f, -0.1950903220f };
constexpr int BR3[8] = {0,4,2,6,1,5,3,7};

template<int KK, bool INV>
__device__ __forceinline__ cplx twid(cplx d) {
  constexpr int K = KK & 31;
  if constexpr (K == 0)       return d;
  else if constexpr (K == 8)  { if constexpr (INV) return cplx{-d.y, d.x}; else return cplx{d.y, -d.x}; }
  else if constexpr (K == 16) return cplx{-d.x, -d.y};
  else if constexpr (K == 24) { if constexpr (INV) return cplx{d.y, -d.x}; else return cplx{-d.y, d.x}; }
  else {
    constexpr float c = W32C32[K];
    constexpr float s = INV ? W32S32[K] : -W32S32[K];
    return cmul(d, cplx{c, s});
  }
}

template<int N, int SP, bool INV>
__device__ __forceinline__ void fft_pass(cplx* z) {
  #pragma unroll
  for (int b = 0; b < N; b += 2*SP) {
    cfor<0, SP>([&](auto rc){
      constexpr int r = decltype(rc)::value;
      constexpr int KK = r * (16 / SP);
      if constexpr (!INV) {
        cplx u = z[b+r], v = z[b+r+SP];
        z[b+r]    = cadd(u, v);
        z[b+r+SP] = twid<KK,false>(csub(u, v));
      } else {
        cplx t0 = z[b+r], t1 = z[b+r+SP];
        cplx w = twid<KK,true>(t1);
        z[b+r]    = cadd(t0, w);
        z[b+r+SP] = csub(t0, w);
      }
    });
  }
}

template<int N, bool INV>
__device__ __forceinline__ void fft_regs(cplx* z) {
  if constexpr (!INV) {
    if constexpr (N >= 32) fft_pass<N,16,false>(z);
    if constexpr (N >= 16) fft_pass<N, 8,false>(z);
    if constexpr (N >=  8) fft_pass<N, 4,false>(z);
    if constexpr (N >=  4) fft_pass<N, 2,false>(z);
    fft_pass<N,1,false>(z);
  } else {
    fft_pass<N,1,true>(z);
    if constexpr (N >=  4) fft_pass<N, 2,true>(z);
    if constexpr (N >=  8) fft_pass<N, 4,true>(z);
    if constexpr (N >= 16) fft_pass<N, 8,true>(z);
    if constexpr (N >= 32) fft_pass<N,16,true>(z);
  }
}

// ---- paired LDS radix-8 stage, S >= 32, float2 plane, all-b128 traffic -----
// Pair of butterflies (r, r+1): every strided input j*S is two ADJACENT
// complexes -> one aligned float4 (ds_*_b128) serves both butterflies.
template<int S, bool INV>
__device__ __forceinline__ void stage8p(float2* sz, int tid) {
  const float ang1 = (INV ? 2.0f : -2.0f) * 3.14159265358979f / (float)(8 * S);
  #pragma unroll 1            // do NOT interleave pairs: live set ~90 regs each
  for (int it = 0; it < 2; ++it) {
    int pp = tid + it * NTH;          // pair index 0..1023
    int bf = 2 * pp;
    int q = bf / S;
    int r = bf - q * S;               // even
    int base = q * (8 * S) + r;       // even -> PADC(base+j*S) even -> 16B ok
    float ta = ang1 * (float)r;
    float tb = ang1 * (float)(r + 1);
    cplx w1a = {__cosf(ta), __sinf(ta)};
    cplx w1b = {__cosf(tb), __sinf(tb)};
    cplx wa[8], wb[8];
    wa[1]=w1a; wa[2]=cmul(w1a,w1a); wa[3]=cmul(wa[2],w1a); wa[4]=cmul(wa[2],wa[2]);
    wa[5]=cmul(wa[4],wa[1]); wa[6]=cmul(wa[4],wa[2]); wa[7]=cmul(wa[4],wa[3]);
    wb[1]=w1b; wb[2]=cmul(w1b,w1b); wb[3]=cmul(wb[2],w1b); wb[4]=cmul(wb[2],wb[2]);
    wb[5]=cmul(wb[4],wb[1]); wb[6]=cmul(wb[4],wb[2]); wb[7]=cmul(wb[4],wb[3]);

    cplx A[8], B[8];
    if constexpr (!INV) {
      cfor<0,8>([&](auto jc){ constexpr int j = decltype(jc)::value;
        float4 v = *reinterpret_cast<const float4*>(&sz[PADC(base + j*S)]);
        A[j] = {v.x, v.y}; B[j] = {v.z, v.w}; });
      fft_regs<8,false>(A);
      fft_regs<8,false>(B);
      cfor<0,8>([&](auto pc){ constexpr int p = decltype(pc)::value;
        constexpr int m = BR3[p];
        cplx oa, ob;
        if constexpr (m == 0) { oa = A[p]; ob = B[p]; }
        else { oa = cmul(A[p], wa[m]); ob = cmul(B[p], wb[m]); }
        *reinterpret_cast<float4*>(&sz[PADC(base + m*S)]) = make_float4(oa.x, oa.y, ob.x, ob.y); });
    } else {
      cfor<0,8>([&](auto pc){ constexpr int p = decltype(pc)::value;
        constexpr int m = BR3[p];
        float4 v = *reinterpret_cast<const float4*>(&sz[PADC(base + m*S)]);
        if constexpr (m == 0) { A[p] = {v.x, v.y}; B[p] = {v.z, v.w}; }
        else { A[p] = cmul(cplx{v.x, v.y}, wa[m]); B[p] = cmul(cplx{v.z, v.w}, wb[m]); } });
      fft_regs<8,true>(A);
      fft_regs<8,true>(B);
      cfor<0,8>([&](auto jc){ constexpr int j = decltype(jc)::value;
        *reinterpret_cast<float4*>(&sz[PADC(base + j*S)]) = make_float4(A[j].x, A[j].y, B[j].x, B[j].y); });
    }
  }
}

// ---- paired S=4 stage: all twiddles constexpr, b128, conflict-free ---------
template<bool INV>
__device__ __forceinline__ void stage8_s4p(float2* sz, int tid) {
  cfor<0,2>([&](auto rrc){
    constexpr int r0 = decltype(rrc)::value * 2;
    int base = tid * 32 + r0;
    cplx A[8], B[8];
    if constexpr (!INV) {
      cfor<0,8>([&](auto jc){ constexpr int j = decltype(jc)::value;
        float4 v = *reinterpret_cast<const float4*>(&sz[PADC(base + j*4)]);
        A[j] = {v.x, v.y}; B[j] = {v.z, v.w}; });
      fft_regs<8,false>(A);
      fft_regs<8,false>(B);
      cfor<0,8>([&](auto pc){ constexpr int p = decltype(pc)::value;
        constexpr int m = BR3[p];
        cplx oa = twid<r0*m, false>(A[p]);
        cplx ob = twid<(r0+1)*m, false>(B[p]);
        *reinterpret_cast<float4*>(&sz[PADC(base + m*4)]) = make_float4(oa.x, oa.y, ob.x, ob.y); });
    } else {
      cfor<0,8>([&](auto pc){ constexpr int p = decltype(pc)::value;
        constexpr int m = BR3[p];
        float4 v = *reinterpret_cast<const float4*>(&sz[PADC(base + m*4)]);
        A[p] = twid<r0*m, true>(cplx{v.x, v.y});
        B[p] = twid<(r0+1)*m, true>(cplx{v.z, v.w}); });
      fft_regs<8,true>(A);
      fft_regs<8,true>(B);
      cfor<0,8>([&](auto jc){ constexpr int j = decltype(jc)::value;
        *reinterpret_cast<float4*>(&sz[PADC(base + j*4)]) = make_float4(A[j].x, A[j].y, B[j].x, B[j].y); });
    }
  });
}

// ---------- kernel 1: K-spectrum precompute into d_ws (scrambled order) -----
__global__ __launch_bounds__(NTH)
void kfft_kernel(const float* __restrict__ kin, float2* __restrict__ kh) {
  __shared__ __align__(16) float2 sz[LDSC];
  const int tid = threadIdx.x;
  const int h = blockIdx.x;
  const float* krow = kin + (size_t)h * LSIG;
  #pragma unroll
  for (int c = 0; c < 8; ++c) {       // 2 complexes / thread / chunk, b128
    int ci = (c * NTH + tid) * 2;
    float2 v = *reinterpret_cast<const float2*>(krow + ci);
    *reinterpret_cast<float4*>(&sz[PADC(ci)]) = make_float4(v.x, 0.f, v.y, 0.f);
    *reinterpret_cast<float4*>(&sz[PADC(ci + LSIG)]) = make_float4(0.f, 0.f, 0.f, 0.f);
  }
  __syncthreads();
  stage8p<2048,false>(sz, tid); __syncthreads();
  stage8p< 256,false>(sz, tid); __syncthreads();
  stage8p<  32,false>(sz, tid); __syncthreads();
  stage8_s4p<false>(sz, tid);   __syncthreads();

  const float scl = 1.0f / (float)NFFT;
  float2* row = kh + (size_t)h * NFFT;
  #pragma unroll
  for (int s = 0; s < 8; ++s) {
    int m = tid + NTH * s;
    int ci = 4 * m;
    float4 f0 = *reinterpret_cast<const float4*>(&sz[PADC(ci)]);
    float4 f1 = *reinterpret_cast<const float4*>(&sz[PADC(ci + 2)]);
    cplx z[4] = { {f0.x, f0.y}, {f0.z, f0.w}, {f1.x, f1.y}, {f1.z, f1.w} };
    fft_regs<4,false>(z);
    *reinterpret_cast<float4*>(row + ci)     = make_float4(z[0].x*scl, z[0].y*scl, z[1].x*scl, z[1].y*scl);
    *reinterpret_cast<float4*>(row + ci + 2) = make_float4(z[2].x*scl, z[2].y*scl, z[3].x*scl, z[3].y*scl);
  }
}

// ---------- kernel 2: conv (512 thr, float2 LDS, all-b128) ------------------
__global__ __launch_bounds__(NTH)
void conv_kernel(const float* __restrict__ u, const float2* __restrict__ kh,
                 float* __restrict__ out) {
  __shared__ __align__(16) float2 sz[LDSC];
  const int tid = threadIdx.x;
  const int bid = blockIdx.x;
  const int h  = bid >> 2;            // 4 same-h blocks temporally adjacent
  const int pr = bid & 3;

  const float* u0 = u + ((size_t)(2*pr) * NH + h) * LSIG;
  const float* u1 = u0 + (size_t)NH * LSIG;
  #pragma unroll
  for (int c = 0; c < 8; ++c) {
    int ci = (c * NTH + tid) * 2;
    float2 a = *reinterpret_cast<const float2*>(u0 + ci);
    float2 b = *reinterpret_cast<const float2*>(u1 + ci);
    *reinterpret_cast<float4*>(&sz[PADC(ci)]) = make_float4(a.x, b.x, a.y, b.y);
    *reinterpret_cast<float4*>(&sz[PADC(ci + LSIG)]) = make_float4(0.f, 0.f, 0.f, 0.f);
  }
  __syncthreads();
  stage8p<2048,false>(sz, tid); __syncthreads();
  stage8p< 256,false>(sz, tid); __syncthreads();
  stage8p<  32,false>(sz, tid); __syncthreads();
  stage8_s4p<false>(sz, tid);   __syncthreads();

  {   // fused per-quad: DFT4 -> multiply K-hat -> inverse DFT4
    const float2* krow = kh + (size_t)h * NFFT;
    #pragma unroll
    for (int s = 0; s < 8; ++s) {
      int m = tid + NTH * s;
      int ci = 4 * m;
      float4 f0 = *reinterpret_cast<const float4*>(&sz[PADC(ci)]);
      float4 f1 = *reinterpret_cast<const float4*>(&sz[PADC(ci + 2)]);
      cplx z[4] = { {f0.x, f0.y}, {f0.z, f0.w}, {f1.x, f1.y}, {f1.z, f1.w} };
      fft_regs<4,false>(z);
      float4 k0 = *reinterpret_cast<const float4*>(krow + ci);
      float4 k1 = *reinterpret_cast<const float4*>(krow + ci + 2);
      z[0] = cmul(z[0], cplx{k0.x, k0.y});
      z[1] = cmul(z[1], cplx{k0.z, k0.w});
      z[2] = cmul(z[2], cplx{k1.x, k1.y});
      z[3] = cmul(z[3], cplx{k1.z, k1.w});
      fft_regs<4,true>(z);
      *reinterpret_cast<float4*>(&sz[PADC(ci)])     = make_float4(z[0].x, z[0].y, z[1].x, z[1].y);
      *reinterpret_cast<float4*>(&sz[PADC(ci + 2)]) = make_float4(z[2].x, z[2].y, z[3].x, z[3].y);
    }
  }
  __syncthreads();
  stage8_s4p<true>(sz, tid);   __syncthreads();
  stage8p<  32,true>(sz, tid); __syncthreads();
  stage8p< 256,true>(sz, tid); __syncthreads();
  stage8p<2048,true>(sz, tid); __syncthreads();

  float* o0 = out + ((size_t)(2*pr) * NH + h) * LSIG;
  float* o1 = o0 + (size_t)NH * LSIG;
  #pragma unroll
  for (int c = 0; c < 4; ++c) {       // 4 complexes / thread / chunk
    int ci = (c * NTH + tid) * 4;
    float4 f0 = *reinterpret_cast<const float4*>(&sz[PADC(ci)]);
    float4 f1 = *reinterpret_cast<const float4*>(&sz[PADC(ci + 2)]);
    *reinterpret_cast<float4*>(o0 + ci) = make_float4(f0.x, f0.z, f1.x, f1.z);
    *reinterpret_cast<float4*>(o1 + ci) = make_float4(f0.y, f0.w, f1.y, f1.w);
  }
}

// ================= fallback (round-9 monolithic, known-good) ================
template<int S, bool INV>
__device__ __forceinline__ void stage8f(float* sre, float* sim, int tid) {
  const float ang1 = (INV ? 2.0f : -2.0f) * 3.14159265358979f / (float)(8 * S);
  #pragma unroll
  for (int it = 0; it < (NFFT/8)/NTH; ++it) {
    int bf = tid + it * NTH;
    int q = bf / S;
    int r = bf - q * S;
    int base = q * (8 * S) + r;
    float t = ang1 * (float)r;
    cplx w1 = {__cosf(t), __sinf(t)};
    cplx wp[8];
    wp[0] = {1.0f, 0.0f};
    wp[1] = w1; wp[2] = cmul(w1, w1); wp[3] = cmul(wp[2], w1); wp[4] = cmul(wp[2], wp[2]);
    wp[5] = cmul(wp[4], wp[1]); wp[6] = cmul(wp[4], wp[2]); wp[7] = cmul(wp[4], wp[3]);
    cplx a[8];
    if constexpr (!INV) {
      cfor<0,8>([&](auto jc){ constexpr int j = decltype(jc)::value;
        int idx = PADI(base + j*S); a[j] = {sre[idx], sim[idx]}; });
      fft_regs<8,false>(a);
      cfor<0,8>([&](auto pc){ constexpr int p = decltype(pc)::value;
        constexpr int m = BR3[p];
        cplx o; if constexpr (m == 0) o = a[p]; else o = cmul(a[p], wp[m]);
        int idx = PADI(base + m*S); sre[idx] = o.x; sim[idx] = o.y; });
    } else {
      cfor<0,8>([&](auto pc){ constexpr int p = decltype(pc)::value;
        constexpr int m = BR3[p];
        int idx = PADI(base + m*S); cplx v = {sre[idx], sim[idx]};
        if constexpr (m == 0) a[p] = v; else a[p] = cmul(v, wp[m]); });
      fft_regs<8,true>(a);
      cfor<0,8>([&](auto jc){ constexpr int j = decltype(jc)::value;
        int idx = PADI(base + j*S); sre[idx] = a[j].x; sim[idx] = a[j].y; });
    }
  }
}

template<bool INV>
__device__ __forceinline__ void stage8_s4f(float* sre, float* sim, int tid) {
  cfor<0,4>([&](auto rc){
    constexpr int r = decltype(rc)::value;
    int base = tid * 32 + r;
    cplx a[8];
    if constexpr (!INV) {
      cfor<0,8>([&](auto jc){ constexpr int j = decltype(jc)::value;
        int idx = PADI(base + j*4); a[j] = {sre[idx], sim[idx]}; });
      fft_regs<8,false>(a);
      cfor<0,8>([&](auto pc){ constexpr int p = decltype(pc)::value;
        constexpr int m = BR3[p];
        cplx o = twid<r*m, false>(a[p]);
        int idx = PADI(base + m*4); sre[idx] = o.x; sim[idx] = o.y; });
    } else {
      cfor<0,8>([&](auto pc){ constexpr int p = decltype(pc)::value;
        constexpr int m = BR3[p];
        int idx = PADI(base + m*4); cplx v = {sre[idx], sim[idx]};
        a[p] = twid<r*m, true>(v); });
      fft_regs<8,true>(a);
      cfor<0,8>([&](auto jc){ constexpr int j = decltype(jc)::value;
        int idx = PADI(base + j*4); sre[idx] = a[j].x; sim[idx] = a[j].y; });
    }
  });
}

__global__ __launch_bounds__(NTH)
void fftconv_fallback(const float* __restrict__ u, const float* __restrict__ kin,
                      float* __restrict__ out) {
  __shared__ float sre[NFFT + (NFFT >> 5)];
  __shared__ float sim[NFFT + (NFFT >> 5)];
  const int tid = threadIdx.x;
  const int bid = blockIdx.x;
  const int h  = bid >> 2;
  const int pr = bid & 3;

  const float* krow = kin + (size_t)h * LSIG;
  #pragma unroll
  for (int c = 0; c < 4; ++c) {
    int i0 = (c * NTH + tid) * 4;
    float4 v = *reinterpret_cast<const float4*>(krow + i0);
    int p0 = PADI(i0);
    sre[p0+0]=v.x; sre[p0+1]=v.y; sre[p0+2]=v.z; sre[p0+3]=v.w;
    sim[p0+0]=0.f; sim[p0+1]=0.f; sim[p0+2]=0.f; sim[p0+3]=0.f;
    int p1 = PADI(i0 + LSIG);
    sre[p1+0]=0.f; sre[p1+1]=0.f; sre[p1+2]=0.f; sre[p1+3]=0.f;
    sim[p1+0]=0.f; sim[p1+1]=0.f; sim[p1+2]=0.f; sim[p1+3]=0.f;
  }
  __syncthreads();
  stage8f<2048,false>(sre, sim, tid); __syncthreads();
  stage8f< 256,false>(sre, sim, tid); __syncthreads();
  stage8f<  32,false>(sre, sim, tid); __syncthreads();
  stage8_s4f<false>(sre, sim, tid);   __syncthreads();

  cplx kq[4][4];
  cplx kq2[4][4];
  const float scl = 1.0f / (float)NFFT;
  #pragma unroll
  for (int s = 0; s < 8; ++s) {
    int m = tid + NTH * s;
    int p = PADI(4 * m);
    cplx z[4] = { {sre[p+0], sim[p+0]}, {sre[p+1], sim[p+1]},
                  {sre[p+2], sim[p+2]}, {sre[p+3], sim[p+3]} };
    fft_regs<4,false>(z);
    #pragma unroll
    for (int e = 0; e < 4; ++e) {
      cplx v = {z[e].x*scl, z[e].y*scl};
      if (s < 4) kq[s][e] = v; else kq2[s-4][e] = v;
    }
  }
  __syncthreads();

  const float* u0 = u + ((size_t)(2*pr) * NH + h) * LSIG;
  const float* u1 = u0 + (size_t)NH * LSIG;
  #pragma unroll
  for (int c = 0; c < 4; ++c) {
    int i0 = (c * NTH + tid) * 4;
    float4 a = *reinterpret_cast<const float4*>(u0 + i0);
    float4 b = *reinterpret_cast<const float4*>(u1 + i0);
    int p0 = PADI(i0);
    sre[p0+0]=a.x; sre[p0+1]=a.y; sre[p0+2]=a.z; sre[p0+3]=a.w;
    sim[p0+0]=b.x; sim[p0+1]=b.y; sim[p0+2]=b.z; sim[p0+3]=b.w;
    int p1 = PADI(i0 + LSIG);
    sre[p1+0]=0.f; sre[p1+1]=0.f; sre[p1+2]=0.f; sre[p1+3]=0.f;
    sim[p1+0]=0.f; sim[p1+1]=0.f; sim[p1+2]=0.f; sim[p1+3]=0.f;
  }
  __syncthreads();
  stage8f<2048,false>(sre, sim, tid); __syncthreads();
  stage8f< 256,false>(sre, sim, tid); __syncthreads();
  stage8f<  32,false>(sre, sim, tid); __syncthreads();
  stage8_s4f<false>(sre, sim, tid);   __syncthreads();

  #pragma unroll
  for (int s = 0; s < 8; ++s) {
    int m = tid + NTH * s;
    int p = PADI(4 * m);
    cplx z[4] = { {sre[p+0], sim[p+0]}, {sre[p+1], sim[p+1]},
                  {sre[p+2], sim[p+2]}, {sre[p+3], sim[p+3]} };
    fft_regs<4,false>(z);
    #pragma unroll
    for (int e = 0; e < 4; ++e) z[e] = cmul(z[e], (s<4) ? kq[s][e] : kq2[s-4][e]);
    fft_regs<4,true>(z);
    #pragma unroll
    for (int e = 0; e < 4; ++e) { sre[p+e] = z[e].x; sim[p+e] = z[e].y; }
  }
  __syncthreads();
  stage8_s4f<true>(sre, sim, tid);   __syncthreads();
  stage8f<  32,true>(sre, sim, tid); __syncthreads();
  stage8f< 256,true>(sre, sim, tid); __syncthreads();
  stage8f<2048,true>(sre, sim, tid); __syncthreads();

  float* o0 = out + ((size_t)(2*pr) * NH + h) * LSIG;
  float* o1 = o0 + (size_t)NH * LSIG;
  #pragma unroll
  for (int c = 0; c < 4; ++c) {
    int i0 = (c * NTH + tid) * 4;
    int p0 = PADI(i0);
    float4 a = {sre[p0], sre[p0+1], sre[p0+2], sre[p0+3]};
    float4 b = {sim[p0], sim[p0+1], sim[p0+2], sim[p0+3]};
    *reinterpret_cast<float4*>(o0 + i0) = a;
    *reinterpret_cast<float4*>(o1 + i0) = b;
  }
}

extern "C" void kernel_launch(void* const* d_in, const int* in_sizes, int n_in,
                              void* d_out, int out_size, void* d_ws, size_t ws_size,
                              hipStream_t stream) {
  (void)in_sizes; (void)n_in; (void)out_size;
  const float* u = (const float*)d_in[0];
  const float* k = (const float*)d_in[1];
  float* out = (float*)d_out;
  const size_t need = (size_t)NH * NFFT * sizeof(float2);   // 128 MiB
  if (ws_size >= need) {
    hipLaunchKernelGGL(kfft_kernel, dim3(NH),   dim3(NTH), 0, stream, k, (float2*)d_ws);
    hipLaunchKernelGGL(conv_kernel, dim3(4096), dim3(NTH), 0, stream, u, (const float2*)d_ws, out);
  } else {
    hipLaunchKernelGGL(fftconv_fallback, dim3(4096), dim3(NTH), 0, stream, u, k, out);
  }
}